// Round 2
// baseline (841.500 us; speedup 1.0000x reference)
//
#include <hip/hip_runtime.h>
#include <hip/hip_bf16.h>
#include <math.h>

#define N_TOK 32768
#define DIM   1024
#define HID   1024
#define NE    8

typedef __bf16 bf16_t;
typedef __bf16 bf16x8 __attribute__((ext_vector_type(8)));
typedef __bf16 bf16x4 __attribute__((ext_vector_type(4)));
typedef float  f32x4  __attribute__((ext_vector_type(4)));

#define GLOAD_LDS(g, s) __builtin_amdgcn_global_load_lds(                      \
    (const __attribute__((address_space(1))) void*)(g),                        \
    (__attribute__((address_space(3))) void*)(s), 16, 0, 0)

// ---------------------------------------------------------------------------
// expert_w f32 [E][D][H]  ->  bf16 [E][H][D]   (transpose so GEMM B is K-contig)
// ---------------------------------------------------------------------------
__global__ __launch_bounds__(256) void convert_w_kernel(const float* __restrict__ W,
                                                        bf16_t* __restrict__ Wt) {
  __shared__ float tile[64][65];
  const int e  = blockIdx.z;
  const int d0 = blockIdx.x * 64;
  const int h0 = blockIdx.y * 64;
  const int t  = threadIdx.x;
  const float* src = W + (size_t)e * DIM * HID;
#pragma unroll
  for (int p = 0; p < 4; ++p) {
    int r = p * 16 + (t >> 4);
    int c = (t & 15) * 4;
    f32x4 v = *(const f32x4*)&src[(size_t)(d0 + r) * HID + h0 + c];
    tile[r][c + 0] = v[0]; tile[r][c + 1] = v[1];
    tile[r][c + 2] = v[2]; tile[r][c + 3] = v[3];
  }
  __syncthreads();
  const int hr = t >> 2, dseg = t & 3;
  bf16_t tmp[16];
#pragma unroll
  for (int j = 0; j < 16; ++j) tmp[j] = (bf16_t)tile[dseg * 16 + j][hr];
  bf16_t* dst = Wt + (size_t)e * HID * DIM + (size_t)(h0 + hr) * DIM + d0 + dseg * 16;
  *(bf16x8*)dst       = *(const bf16x8*)tmp;
  *(bf16x8*)(dst + 8) = *(const bf16x8*)(tmp + 8);
}

// ---------------------------------------------------------------------------
// Fused router: x f32 -> x bf16 copy, fp64 logits, top-2 + softmax,
// block-aggregated scatter into per-expert compact lists.
// ---------------------------------------------------------------------------
__global__ __launch_bounds__(256) void router_kernel(
    const float* __restrict__ x, const float* __restrict__ rw,
    const float* __restrict__ rb, bf16_t* __restrict__ xb,
    int* __restrict__ tok_list, float* __restrict__ w_list,
    int* __restrict__ gcnt) {
  __shared__ float rws[NE * DIM];
  __shared__ int   ce0[64], ce1[64];
  __shared__ float cw0[64], cw1[64];
  __shared__ int   lp0[64], lp1[64];
  __shared__ int   lcnt[NE], gbase[NE];
  const int t = threadIdx.x;
#pragma unroll
  for (int p = 0; p < 8; ++p) {                 // stage router_w (32 KB) in LDS
    int i4 = p * 256 + t;
    *(f32x4*)&rws[i4 * 4] = *(const f32x4*)&rw[i4 * 4];
  }
  if (t < NE) lcnt[t] = 0;
  __syncthreads();

  const int w = t >> 6, l = t & 63, ts = l >> 4, sub = l & 15;
  const int base = blockIdx.x * 64;
  for (int it = 0; it < 4; ++it) {
    const int lt    = it * 16 + w * 4 + ts;
    const int token = base + lt;
    const float* xrow  = x  + (size_t)token * DIM;
    bf16_t*      xbrow = xb + (size_t)token * DIM;
    double acc[NE];
#pragma unroll
    for (int e = 0; e < NE; ++e) acc[e] = 0.0;
    for (int p = 0; p < 16; ++p) {
      const int d = p * 64 + sub * 4;
      f32x4 xv = *(const f32x4*)&xrow[d];
      bf16x4 bv;
#pragma unroll
      for (int j = 0; j < 4; ++j) bv[j] = (bf16_t)xv[j];
      *(bf16x4*)&xbrow[d] = bv;
#pragma unroll
      for (int e = 0; e < NE; ++e) {
        f32x4 rv = *(const f32x4*)&rws[e * DIM + d];
        acc[e] += (double)xv[0] * (double)rv[0] + (double)xv[1] * (double)rv[1]
                + (double)xv[2] * (double)rv[2] + (double)xv[3] * (double)rv[3];
      }
    }
#pragma unroll
    for (int e = 0; e < NE; ++e) {              // reduce across the 16 lanes
      double v = acc[e];
      v += __shfl_xor(v, 1, 16);
      v += __shfl_xor(v, 2, 16);
      v += __shfl_xor(v, 4, 16);
      v += __shfl_xor(v, 8, 16);
      acc[e] = v;
    }
    if (sub == 0) {
      double lv[NE];
#pragma unroll
      for (int e = 0; e < NE; ++e) lv[e] = acc[e] + (double)rb[e];
      int e0 = 0; double v0 = lv[0];
#pragma unroll
      for (int e = 1; e < NE; ++e) if (lv[e] > v0) { v0 = lv[e]; e0 = e; }
      int e1 = -1; double v1 = -1.0e300;
#pragma unroll
      for (int e = 0; e < NE; ++e) if (e != e0 && lv[e] > v1) { v1 = lv[e]; e1 = e; }
      const float ef = expf((float)(v1 - v0));
      const float s  = 1.0f + ef;
      ce0[lt] = e0; ce1[lt] = e1;
      cw0[lt] = 1.0f / s; cw1[lt] = ef / s;
    }
  }
  __syncthreads();
  if (t < 64) {                                  // local offsets (LDS atomics)
    lp0[t] = atomicAdd(&lcnt[ce0[t]], 1);
    lp1[t] = atomicAdd(&lcnt[ce1[t]], 1);
  }
  __syncthreads();
  if (t < NE) gbase[t] = atomicAdd(&gcnt[t], lcnt[t]);   // one atomic/expert/block
  __syncthreads();
  if (t < 64) {
    const int token = base + t;
    const int e0 = ce0[t], e1 = ce1[t];
    const int p0 = gbase[e0] + lp0[t];
    const int p1 = gbase[e1] + lp1[t];
    tok_list[e0 * N_TOK + p0] = token;  w_list[e0 * N_TOK + p0] = cw0[t];
    tok_list[e1 * N_TOK + p1] = token;  w_list[e1 * N_TOK + p1] = cw1[t];
  }
}

// ---------------------------------------------------------------------------
// Grouped GEMM, 256x256 tile, BK=64, 8 waves (2Mx4N), double-buffered LDS,
// 2-phase prefetch (stage next K-tile BEFORE computing current; one barrier
// per K-step; barrier drains vmcnt). Epilogue: atomicAdd w*(acc+bias).
// ---------------------------------------------------------------------------
#define BM 256
#define BN 256
#define BK 64

#define STAGE(Ad, Bd, K0) do {                                   \
    GLOAD_LDS(aptr0 + (K0), (Ad) + 0 * 4096 + ldoff);            \
    GLOAD_LDS(bptr0 + (K0), (Bd) + 0 * 4096 + ldoff);            \
    GLOAD_LDS(aptr1 + (K0), (Ad) + 1 * 4096 + ldoff);            \
    GLOAD_LDS(bptr1 + (K0), (Bd) + 1 * 4096 + ldoff);            \
    GLOAD_LDS(aptr2 + (K0), (Ad) + 2 * 4096 + ldoff);            \
    GLOAD_LDS(bptr2 + (K0), (Bd) + 2 * 4096 + ldoff);            \
    GLOAD_LDS(aptr3 + (K0), (Ad) + 3 * 4096 + ldoff);            \
    GLOAD_LDS(bptr3 + (K0), (Bd) + 3 * 4096 + ldoff);            \
  } while (0)

__global__ __launch_bounds__(512, 1) void moe_gemm_kernel(
    const bf16_t* __restrict__ xb, const bf16_t* __restrict__ wt,
    const float* __restrict__ eb, const int* __restrict__ tok_list,
    const float* __restrict__ w_list, const int* __restrict__ gcnt,
    float* __restrict__ out) {
  const int e  = blockIdx.z;
  const int c  = gcnt[e];
  const int m0 = blockIdx.x * BM;
  if (m0 >= c) return;
  const int h0 = blockIdx.y * BN;

  extern __shared__ char smem[];
  bf16_t* A0 = (bf16_t*)smem;          // [256][64] bf16 = 32 KB
  bf16_t* A1 = A0 + BM * BK;
  bf16_t* B0 = A1 + BM * BK;
  bf16_t* B1 = B0 + BN * BK;

  __shared__ int   tok_s[BM];
  __shared__ float w_s[BM];

  const int t = threadIdx.x;
  if (t < BM) {
    int r  = m0 + t;
    int rc = r < c ? r : c - 1;       // clamp padded rows to a valid gather row
    tok_s[t] = tok_list[e * N_TOK + rc];
    w_s[t]   = (r < c) ? w_list[e * N_TOK + r] : 0.0f;   // weight 0 kills pads
  }
  __syncthreads();

  // ---- staging addresses: thread t loads rows {p*64 + t>>3}, seg t&7 ----
  const int srow = t >> 3, sseg = t & 7;
  const int ldoff = srow * BK + sseg * 8;       // elem offset inside [256][64]
  const bf16_t* wbase = wt + (size_t)e * HID * DIM;
  const bf16_t* aptr0 = xb + (size_t)tok_s[0 * 64 + srow] * DIM + sseg * 8;
  const bf16_t* aptr1 = xb + (size_t)tok_s[1 * 64 + srow] * DIM + sseg * 8;
  const bf16_t* aptr2 = xb + (size_t)tok_s[2 * 64 + srow] * DIM + sseg * 8;
  const bf16_t* aptr3 = xb + (size_t)tok_s[3 * 64 + srow] * DIM + sseg * 8;
  const bf16_t* bptr0 = wbase + (size_t)(h0 + 0 * 64 + srow) * DIM + sseg * 8;
  const bf16_t* bptr1 = wbase + (size_t)(h0 + 1 * 64 + srow) * DIM + sseg * 8;
  const bf16_t* bptr2 = wbase + (size_t)(h0 + 2 * 64 + srow) * DIM + sseg * 8;
  const bf16_t* bptr3 = wbase + (size_t)(h0 + 3 * 64 + srow) * DIM + sseg * 8;

  // ---- MFMA geometry: 8 waves as 2M x 4N; per-wave output 128x64 ----
  const int w  = t >> 6, l = t & 63;
  const int wr = w >> 2, wc = w & 3;
  const int fr = l & 15, fq = l >> 4;

  f32x4 acc[8][4];
  const f32x4 fzero = {0.0f, 0.0f, 0.0f, 0.0f};
#pragma unroll
  for (int m = 0; m < 8; ++m)
#pragma unroll
    for (int n = 0; n < 4; ++n) acc[m][n] = fzero;

  STAGE(A0, B0, 0);
  __syncthreads();                               // drains vmcnt(0)

  for (int kt = 0; kt < DIM / BK; ++kt) {
    bf16_t* Ac = (kt & 1) ? A1 : A0;
    bf16_t* Bc = (kt & 1) ? B1 : B0;
    if (kt < DIM / BK - 1) {
      bf16_t* An = (kt & 1) ? A0 : A1;
      bf16_t* Bn = (kt & 1) ? B0 : B1;
      STAGE(An, Bn, (kt + 1) * BK);              // prefetch BEFORE compute
    }
#pragma unroll
    for (int kk = 0; kk < 2; ++kk) {
      bf16x8 af[8], bfr[4];
#pragma unroll
      for (int m = 0; m < 8; ++m)
        af[m] = *(const bf16x8*)&Ac[(wr * 128 + m * 16 + fr) * BK + kk * 32 + fq * 8];
#pragma unroll
      for (int n = 0; n < 4; ++n)
        bfr[n] = *(const bf16x8*)&Bc[(wc * 64 + n * 16 + fr) * BK + kk * 32 + fq * 8];
#pragma unroll
      for (int m = 0; m < 8; ++m)
#pragma unroll
        for (int n = 0; n < 4; ++n)
          acc[m][n] = __builtin_amdgcn_mfma_f32_16x16x32_bf16(af[m], bfr[n],
                                                              acc[m][n], 0, 0, 0);
    }
    __syncthreads();            // drains lgkm + vmcnt: next tile ready, buffer free
  }

#pragma unroll
  for (int n = 0; n < 4; ++n) {
    const int h    = h0 + wc * 64 + n * 16 + fr;
    const float bias = eb[e * HID + h];
#pragma unroll
    for (int m = 0; m < 8; ++m) {
#pragma unroll
      for (int q = 0; q < 4; ++q) {
        const int r  = wr * 128 + m * 16 + fq * 4 + q;
        const float wv = w_s[r];
        if (wv != 0.0f) {
          atomicAdd(&out[(size_t)tok_s[r] * HID + h], wv * (acc[m][n][q] + bias));
        }
      }
    }
  }
}

// ---------------------------------------------------------------------------
extern "C" void kernel_launch(void* const* d_in, const int* in_sizes, int n_in,
                              void* d_out, int out_size, void* d_ws, size_t ws_size,
                              hipStream_t stream) {
  const float* x  = (const float*)d_in[0];
  const float* rw = (const float*)d_in[1];
  const float* rb = (const float*)d_in[2];
  const float* ew = (const float*)d_in[3];
  const float* eb = (const float*)d_in[4];
  float* out = (float*)d_out;

  char* ws = (char*)d_ws;
  bf16_t* xb       = (bf16_t*)(ws);                        // 64 MB
  bf16_t* wt       = (bf16_t*)(ws + 67108864);             // 16 MB
  int*    tok_list = (int*)   (ws + 83886080);             // 1 MB
  float*  w_list   = (float*) (ws + 84934656);             // 1 MB
  int*    gcnt     = (int*)   (ws + 85983232);             // 32 B

  hipMemsetAsync(gcnt, 0, NE * sizeof(int), stream);
  hipMemsetAsync(d_out, 0, (size_t)out_size * sizeof(float), stream);

  convert_w_kernel<<<dim3(DIM / 64, HID / 64, NE), 256, 0, stream>>>(ew, wt);
  router_kernel<<<dim3(N_TOK / 64), 256, 0, stream>>>(x, rw, rb, xb,
                                                      tok_list, w_list, gcnt);

  hipFuncSetAttribute((const void*)moe_gemm_kernel,
                      hipFuncAttributeMaxDynamicSharedMemorySize, 131072);
  moe_gemm_kernel<<<dim3(N_TOK / BM, HID / BN, NE), 512, 131072, stream>>>(
      xb, wt, eb, tok_list, w_list, gcnt, out);
}

// Round 3
// 577.775 us; speedup vs baseline: 1.4564x; 1.4564x over previous
//
#include <hip/hip_runtime.h>
#include <hip/hip_bf16.h>
#include <math.h>

#define N_TOK 32768
#define DIM   1024
#define HID   1024
#define NE    8
#define GX    64          // row-tile capacity per (expert,slot): 64*128 = 8192 rows

typedef __bf16 bf16_t;
typedef __bf16 bf16x8 __attribute__((ext_vector_type(8)));
typedef __bf16 bf16x4 __attribute__((ext_vector_type(4)));
typedef float  f32x4  __attribute__((ext_vector_type(4)));

#define GLOAD_LDS(g, s) __builtin_amdgcn_global_load_lds(                      \
    (const __attribute__((address_space(1))) void*)(g),                        \
    (__attribute__((address_space(3))) void*)(s), 16, 0, 0)

// ---------------------------------------------------------------------------
// expert_w f32 [E][D][H]  ->  bf16 [E][H][D]   (transpose so GEMM B is K-contig)
// ---------------------------------------------------------------------------
__global__ __launch_bounds__(256) void convert_w_kernel(const float* __restrict__ W,
                                                        bf16_t* __restrict__ Wt) {
  __shared__ float tile[64][65];
  const int e  = blockIdx.z;
  const int d0 = blockIdx.x * 64;
  const int h0 = blockIdx.y * 64;
  const int t  = threadIdx.x;
  const float* src = W + (size_t)e * DIM * HID;
#pragma unroll
  for (int p = 0; p < 4; ++p) {
    int r = p * 16 + (t >> 4);
    int c = (t & 15) * 4;
    f32x4 v = *(const f32x4*)&src[(size_t)(d0 + r) * HID + h0 + c];
    tile[r][c + 0] = v[0]; tile[r][c + 1] = v[1];
    tile[r][c + 2] = v[2]; tile[r][c + 3] = v[3];
  }
  __syncthreads();
  const int hr = t >> 2, dseg = t & 3;
  bf16_t tmp[16];
#pragma unroll
  for (int j = 0; j < 16; ++j) tmp[j] = (bf16_t)tile[dseg * 16 + j][hr];
  bf16_t* dst = Wt + (size_t)e * HID * DIM + (size_t)(h0 + hr) * DIM + d0 + dseg * 16;
  *(bf16x8*)dst       = *(const bf16x8*)tmp;
  *(bf16x8*)(dst + 8) = *(const bf16x8*)(tmp + 8);
}

// ---------------------------------------------------------------------------
// Fused router: x f32 -> x bf16 copy, fp64 logits, top-2 + softmax,
// block-aggregated scatter into 16 per-(expert,slot) compact lists.
// list id le = e*2 + slot  (slot 0 = top-1 choice, slot 1 = top-2 choice)
// ---------------------------------------------------------------------------
__global__ __launch_bounds__(256) void router_kernel(
    const float* __restrict__ x, const float* __restrict__ rw,
    const float* __restrict__ rb, bf16_t* __restrict__ xb,
    int* __restrict__ tok_list, float* __restrict__ w_list,
    int* __restrict__ gcnt) {
  __shared__ float rws[NE * DIM];
  __shared__ int   ce0[64], ce1[64];
  __shared__ float cw0[64], cw1[64];
  __shared__ int   lp0[64], lp1[64];
  __shared__ int   lcnt[2 * NE], gbase[2 * NE];
  const int t = threadIdx.x;
#pragma unroll
  for (int p = 0; p < 8; ++p) {                 // stage router_w (32 KB) in LDS
    int i4 = p * 256 + t;
    *(f32x4*)&rws[i4 * 4] = *(const f32x4*)&rw[i4 * 4];
  }
  if (t < 2 * NE) lcnt[t] = 0;
  __syncthreads();

  const int w = t >> 6, l = t & 63, ts = l >> 4, sub = l & 15;
  const int base = blockIdx.x * 64;
  for (int it = 0; it < 4; ++it) {
    const int lt    = it * 16 + w * 4 + ts;
    const int token = base + lt;
    const float* xrow  = x  + (size_t)token * DIM;
    bf16_t*      xbrow = xb + (size_t)token * DIM;
    double acc[NE];
#pragma unroll
    for (int e = 0; e < NE; ++e) acc[e] = 0.0;
    for (int p = 0; p < 16; ++p) {
      const int d = p * 64 + sub * 4;
      f32x4 xv = *(const f32x4*)&xrow[d];
      bf16x4 bv;
#pragma unroll
      for (int j = 0; j < 4; ++j) bv[j] = (bf16_t)xv[j];
      *(bf16x4*)&xbrow[d] = bv;
#pragma unroll
      for (int e = 0; e < NE; ++e) {
        f32x4 rv = *(const f32x4*)&rws[e * DIM + d];
        acc[e] += (double)xv[0] * (double)rv[0] + (double)xv[1] * (double)rv[1]
                + (double)xv[2] * (double)rv[2] + (double)xv[3] * (double)rv[3];
      }
    }
#pragma unroll
    for (int e = 0; e < NE; ++e) {              // reduce across the 16 lanes
      double v = acc[e];
      v += __shfl_xor(v, 1, 16);
      v += __shfl_xor(v, 2, 16);
      v += __shfl_xor(v, 4, 16);
      v += __shfl_xor(v, 8, 16);
      acc[e] = v;
    }
    if (sub == 0) {
      double lv[NE];
#pragma unroll
      for (int e = 0; e < NE; ++e) lv[e] = acc[e] + (double)rb[e];
      int e0 = 0; double v0 = lv[0];
#pragma unroll
      for (int e = 1; e < NE; ++e) if (lv[e] > v0) { v0 = lv[e]; e0 = e; }
      int e1 = -1; double v1 = -1.0e300;
#pragma unroll
      for (int e = 0; e < NE; ++e) if (e != e0 && lv[e] > v1) { v1 = lv[e]; e1 = e; }
      const float ef = expf((float)(v1 - v0));
      const float s  = 1.0f + ef;
      ce0[lt] = e0; ce1[lt] = e1;
      cw0[lt] = 1.0f / s; cw1[lt] = ef / s;
    }
  }
  __syncthreads();
  if (t < 64) {                                  // local offsets (LDS atomics)
    lp0[t] = atomicAdd(&lcnt[ce0[t] * 2 + 0], 1);
    lp1[t] = atomicAdd(&lcnt[ce1[t] * 2 + 1], 1);
  }
  __syncthreads();
  if (t < 2 * NE) gbase[t] = atomicAdd(&gcnt[t], lcnt[t]);  // 1 atomic/list/block
  __syncthreads();
  if (t < 64) {
    const int token = base + t;
    const int le0 = ce0[t] * 2 + 0, le1 = ce1[t] * 2 + 1;
    const int p0 = gbase[le0] + lp0[t];
    const int p1 = gbase[le1] + lp1[t];
    tok_list[le0 * N_TOK + p0] = token;  w_list[le0 * N_TOK + p0] = cw0[t];
    tok_list[le1 * N_TOK + p1] = token;  w_list[le1 * N_TOK + p1] = cw1[t];
  }
}

// ---------------------------------------------------------------------------
// Grouped GEMM (m97 structure): 128x128 tile, BK=32, 4 waves (2x2), 16x16x32
// MFMA, global_load_lds staging with BOTH-SIDES LDS swizzle:
//   LDS[row][slot] holds data (row, kseg = slot ^ (row&3)); the global SOURCE
//   address carries the XOR (gload_lds dest must stay linear, rule #21); the
//   ds_read applies the same XOR -> 8 disjoint bank-quads = conflict-free.
// Epilogue: slot 0 pass plain-stores w*(acc+bias); slot 1 pass += (unique
// owner per (slot,token) row -> NO atomics, and no out-zeroing needed).
// XCD swizzle: 4096 blocks, each XCD owns one expert (its 2MB W panel in L2).
// ---------------------------------------------------------------------------
#define BM 128
#define BN 128
#define BK 32

__global__ __launch_bounds__(256) void moe_gemm_kernel(
    const bf16_t* __restrict__ xb, const bf16_t* __restrict__ wt,
    const float* __restrict__ eb, const int* __restrict__ tok_list,
    const float* __restrict__ w_list, const int* __restrict__ gcnt,
    float* __restrict__ out, int slot) {
  // bijective XCD swizzle: nwg = GX*8*NE = 4096 (divisible by 8)
  const int f  = blockIdx.x + GX * (blockIdx.y + (HID / BN) * blockIdx.z);
  const int wg = (f & 7) * (GX * (HID / BN) * NE / 8) + (f >> 3);
  const int bx = wg % GX;
  const int by = (wg / GX) % (HID / BN);
  const int e  = wg / (GX * (HID / BN));

  const int le = e * 2 + slot;
  const int c  = gcnt[le];
  const int m0 = bx * BM;
  if (m0 >= c) return;
  const int h0 = by * BN;

  __shared__ bf16_t As[BM * BK];
  __shared__ bf16_t Bs[BN * BK];
  __shared__ int    tok_s[BM];
  __shared__ float  w_s[BM];

  const int t = threadIdx.x;
  if (t < BM) {
    int r  = m0 + t;
    int rc = r < c ? r : c - 1;       // clamp padded rows to a valid gather row
    tok_s[t] = tok_list[le * N_TOK + rc];
    w_s[t]   = (r < c) ? w_list[le * N_TOK + r] : 0.0f;   // weight 0 kills pads
  }
  __syncthreads();

  const int w  = t >> 6, l = t & 63;
  const int wr = w >> 1, wc = w & 1;
  const int srow = t >> 2, sslot = t & 3;
  const int sx = (sslot ^ (srow & 3)) * 8;      // pre-swizzled source k-segment

  const bf16_t* ag0 = xb + (size_t)tok_s[srow] * DIM + sx;
  const bf16_t* ag1 = xb + (size_t)tok_s[srow + 64] * DIM + sx;
  const bf16_t* wbase = wt + (size_t)e * HID * DIM;
  const bf16_t* bg0 = wbase + (size_t)(h0 + srow) * DIM + sx;
  const bf16_t* bg1 = wbase + (size_t)(h0 + srow + 64) * DIM + sx;

  f32x4 acc[4][4];
  const f32x4 fzero = {0.0f, 0.0f, 0.0f, 0.0f};
#pragma unroll
  for (int m = 0; m < 4; ++m)
#pragma unroll
    for (int n = 0; n < 4; ++n) acc[m][n] = fzero;

  const int fr = l & 15, fq = l >> 4;
  const int rdx = (fq ^ (fr & 3)) * 8;          // swizzled read k-segment

  for (int k0 = 0; k0 < DIM; k0 += BK) {
    GLOAD_LDS(ag0 + k0, As + w * 512);          // rows 0..63   of A tile
    GLOAD_LDS(ag1 + k0, As + 2048 + w * 512);   // rows 64..127 of A tile
    GLOAD_LDS(bg0 + k0, Bs + w * 512);          // rows 0..63   of B tile
    GLOAD_LDS(bg1 + k0, Bs + 2048 + w * 512);   // rows 64..127 of B tile
    __syncthreads();                             // compiler drains vmcnt here

    bf16x8 af[4], bfg[4];
#pragma unroll
    for (int m = 0; m < 4; ++m)
      af[m] = *(const bf16x8*)&As[(wr * 64 + m * 16 + fr) * BK + rdx];
#pragma unroll
    for (int n = 0; n < 4; ++n)
      bfg[n] = *(const bf16x8*)&Bs[(wc * 64 + n * 16 + fr) * BK + rdx];
#pragma unroll
    for (int m = 0; m < 4; ++m)
#pragma unroll
      for (int n = 0; n < 4; ++n)
        acc[m][n] = __builtin_amdgcn_mfma_f32_16x16x32_bf16(af[m], bfg[n],
                                                            acc[m][n], 0, 0, 0);
    __syncthreads();
  }

#pragma unroll
  for (int n = 0; n < 4; ++n) {
    const int h    = h0 + wc * 64 + n * 16 + fr;
    const float bias = eb[e * HID + h];
#pragma unroll
    for (int m = 0; m < 4; ++m) {
#pragma unroll
      for (int q = 0; q < 4; ++q) {
        const int r  = wr * 64 + m * 16 + fq * 4 + q;   // C row = (l>>4)*4+q
        const float wv = w_s[r];
        if (wv != 0.0f) {                                // skips pads only
          const size_t o = (size_t)tok_s[r] * HID + h;
          const float  v = wv * (acc[m][n][q] + bias);
          if (slot == 0) out[o] = v;                     // unique writer
          else           out[o] = out[o] + v;            // unique owner, ordered
        }
      }
    }
  }
}

// ---------------------------------------------------------------------------
extern "C" void kernel_launch(void* const* d_in, const int* in_sizes, int n_in,
                              void* d_out, int out_size, void* d_ws, size_t ws_size,
                              hipStream_t stream) {
  const float* x  = (const float*)d_in[0];
  const float* rw = (const float*)d_in[1];
  const float* rb = (const float*)d_in[2];
  const float* ew = (const float*)d_in[3];
  const float* eb = (const float*)d_in[4];
  float* out = (float*)d_out;

  char* ws = (char*)d_ws;
  bf16_t* xb       = (bf16_t*)(ws);                        // 64 MB
  bf16_t* wt       = (bf16_t*)(ws + 67108864);             // 16 MB
  int*    tok_list = (int*)   (ws + 83886080);             // 2 MB (16 lists)
  float*  w_list   = (float*) (ws + 85983232);             // 2 MB
  int*    gcnt     = (int*)   (ws + 88080384);             // 64 B

  hipMemsetAsync(gcnt, 0, 2 * NE * sizeof(int), stream);

  convert_w_kernel<<<dim3(DIM / 64, HID / 64, NE), 256, 0, stream>>>(ew, wt);
  router_kernel<<<dim3(N_TOK / 64), 256, 0, stream>>>(x, rw, rb, xb,
                                                      tok_list, w_list, gcnt);

  dim3 grid(GX, HID / BN, NE);
  moe_gemm_kernel<<<grid, 256, 0, stream>>>(xb, wt, eb, tok_list, w_list, gcnt,
                                            out, 0);
  moe_gemm_kernel<<<grid, 256, 0, stream>>>(xb, wt, eb, tok_list, w_list, gcnt,
                                            out, 1);
}